// Round 16
// baseline (301.144 us; speedup 1.0000x reference)
//
#include <hip/hip_runtime.h>

#define N_NODES 50000
#define N_EDGES 800000
#define E_TOT   850000
#define F_IN    128
#define HC      256      // H * C_hid
#define NH      8
#define C_OUT   10
#define N_GRAPH 128
#define NBLK    49       // ceil(N_NODES / 1024)
#define XSTRIDE 16       // xh2 row stride: [o0..o9, s2, d2, pad x4] = one 64B line
#define NB_DEG  3322     // ceil(E_TOT / 256)

typedef __attribute__((ext_vector_type(8))) short bf16x8;
typedef __attribute__((ext_vector_type(4))) float f32x4;
typedef __attribute__((ext_vector_type(2))) float f32x2;

__device__ __forceinline__ float lrelu(float x){ return x > 0.f ? x : 0.2f * x; }
__device__ __forceinline__ float elu1(float x){ return x > 0.f ? x : (__expf(x) - 1.f); }

__device__ __forceinline__ unsigned short f2bf(float f){
    unsigned int u = __float_as_uint(f);
    return (unsigned short)((u + 0x7fffu + ((u >> 16) & 1u)) >> 16);
}
__device__ __forceinline__ float bf2f(unsigned short h){
    return __uint_as_float((unsigned int)h << 16);
}
// fp8 e4m3 (OCP) encode via HW converter, RNE
__device__ __forceinline__ unsigned char f2fp8(float v){
    unsigned int t = __builtin_amdgcn_cvt_pk_fp8_f32(v, 0.f, 0, false);
    return (unsigned char)(t & 0xffu);
}

// ---- setup: deg histogram (deg pre-zeroed by memsetAsync) + B split build + W2 transpose ----
__global__ void k_setup(const int* __restrict__ ei, int* __restrict__ deg,
                        const float* __restrict__ W1, unsigned short* __restrict__ bt,
                        const float* __restrict__ W2, float* __restrict__ W2t){
    int b = blockIdx.x;
    if (b < NB_DEG){
        int e = b * 256 + threadIdx.x;
        if (e < E_TOT){
            int dst = (e < N_EDGES) ? ei[N_EDGES + e] : (e - N_EDGES);
            atomicAdd(deg + dst, 1);
        }
    } else if (b < NB_DEG + 128){
        int k = b - NB_DEG;           // 0..127
        int c = threadIdx.x;          // 0..255
        float v = W1[k * HC + c];
        unsigned short hi = f2bf(v);
        unsigned short lo = f2bf(v - bf2f(hi));
        bt[(size_t)c * 256 + k]       = hi;   // col-major: [hi(128) | lo(128)] per col
        bt[(size_t)c * 256 + 128 + k] = lo;
    } else {
        for (int j = threadIdx.x; j < HC * C_OUT; j += 256){
            int k = j / C_OUT, c = j % C_OUT;
            W2t[c * HC + k] = W2[j];
        }
    }
}

// ---- GEMM1 via MFMA (R13-best): 32 rows/wave, 3-way accumulator ILP split,
//      software-prefetched B, fp8 C-tile in LDS, contiguous 256 B row stores ----
__global__ __launch_bounds__(256) void k_gemm1m(const float* __restrict__ x,
                                                const unsigned short* __restrict__ bt,
                                                const float* __restrict__ atts,
                                                const float* __restrict__ attd,
                                                unsigned int* __restrict__ xhb,   // fp8 rows, 64 uints
                                                float* __restrict__ a_s,
                                                float* __restrict__ a_d){
    __shared__ unsigned char tile[4][32][264];    // fp8 C-tile per wave (33.8 KB)
    __shared__ float sc[4][32][8], dc[4][32][8];  // per-row per-head scores (8 KB)
    const int wave = threadIdx.x >> 6, lane = threadIdx.x & 63;
    const int quad = lane >> 4, lidx = lane & 15;
    const int m0 = blockIdx.x * 128 + wave * 32;
    int ar0 = m0 + lidx;      if (ar0 >= N_NODES) ar0 = N_NODES - 1;
    int ar1 = m0 + 16 + lidx; if (ar1 >= N_NODES) ar1 = N_NODES - 1;

    // load x rows, split into hi/lo bf16 fragments in-register
    bf16x8 ah0[4], al0[4], ah1[4], al1[4];
    #pragma unroll
    for (int ks = 0; ks < 4; ks++){
        const float* p0 = x + (size_t)ar0 * F_IN + ks * 32 + quad * 8;
        const float* p1 = x + (size_t)ar1 * F_IN + ks * 32 + quad * 8;
        float4 u0 = *(const float4*)p0, u1 = *(const float4*)(p0 + 4);
        float4 w0 = *(const float4*)p1, w1 = *(const float4*)(p1 + 4);
        float v0[8] = {u0.x,u0.y,u0.z,u0.w,u1.x,u1.y,u1.z,u1.w};
        float v1[8] = {w0.x,w0.y,w0.z,w0.w,w1.x,w1.y,w1.z,w1.w};
        bf16x8 h0v, l0v, h1v, l1v;
        #pragma unroll
        for (int j = 0; j < 8; j++){
            unsigned short hh = f2bf(v0[j]);
            h0v[j] = (short)hh;
            l0v[j] = (short)f2bf(v0[j] - bf2f(hh));
            unsigned short hg = f2bf(v1[j]);
            h1v[j] = (short)hg;
            l1v[j] = (short)f2bf(v1[j] - bf2f(hg));
        }
        ah0[ks] = h0v; al0[ks] = l0v; ah1[ks] = h1v; al1[ks] = l1v;
    }

    const uint4* bbase = (const uint4*)bt;        // col stride = 512 B = 32 uint4
    // preload B for t=0 (h=0, sub=0)
    bf16x8 bh[4], bl[4];
    {
        const uint4* bcol = bbase + (size_t)lidx * 32 + quad;
        #pragma unroll
        for (int ks = 0; ks < 4; ks++){
            bh[ks] = __builtin_bit_cast(bf16x8, bcol[ks * 4]);
            bl[ks] = __builtin_bit_cast(bf16x8, bcol[16 + ks * 4]);
        }
    }
    for (int h = 0; h < NH; h++){
        float ss0[4] = {0,0,0,0}, ss1[4] = {0,0,0,0};
        float dd0[4] = {0,0,0,0}, dd1[4] = {0,0,0,0};
        #pragma unroll
        for (int sub = 0; sub < 2; sub++){
            int col = h * 32 + sub * 16 + lidx;
            // prefetch next (h,sub)'s B before issuing this tile's MFMAs
            bf16x8 nh[4], nl[4];
            int tn = h * 2 + sub + 1;
            if (tn < 16){
                int ncol = (tn >> 1) * 32 + (tn & 1) * 16 + lidx;
                const uint4* nb = bbase + (size_t)ncol * 32 + quad;
                #pragma unroll
                for (int ks = 0; ks < 4; ks++){
                    nh[ks] = __builtin_bit_cast(bf16x8, nb[ks * 4]);
                    nl[ks] = __builtin_bit_cast(bf16x8, nb[16 + ks * 4]);
                }
            }
            // 3-way ILP split: chains of depth 4 instead of 12
            f32x4 a0A = {0.f,0.f,0.f,0.f}, a0B = {0.f,0.f,0.f,0.f}, a0C = {0.f,0.f,0.f,0.f};
            f32x4 a1A = {0.f,0.f,0.f,0.f}, a1B = {0.f,0.f,0.f,0.f}, a1C = {0.f,0.f,0.f,0.f};
            #pragma unroll
            for (int ks = 0; ks < 4; ks++){
                a0A = __builtin_amdgcn_mfma_f32_16x16x32_bf16(ah0[ks], bh[ks], a0A, 0, 0, 0);
                a1A = __builtin_amdgcn_mfma_f32_16x16x32_bf16(ah1[ks], bh[ks], a1A, 0, 0, 0);
                a0B = __builtin_amdgcn_mfma_f32_16x16x32_bf16(ah0[ks], bl[ks], a0B, 0, 0, 0);
                a1B = __builtin_amdgcn_mfma_f32_16x16x32_bf16(ah1[ks], bl[ks], a1B, 0, 0, 0);
                a0C = __builtin_amdgcn_mfma_f32_16x16x32_bf16(al0[ks], bh[ks], a0C, 0, 0, 0);
                a1C = __builtin_amdgcn_mfma_f32_16x16x32_bf16(al1[ks], bh[ks], a1C, 0, 0, 0);
            }
            f32x4 acc0, acc1;
            #pragma unroll
            for (int reg = 0; reg < 4; reg++){
                acc0[reg] = (a0A[reg] + a0B[reg]) + a0C[reg];
                acc1[reg] = (a1A[reg] + a1B[reg]) + a1C[reg];
            }
            float sv = atts[col], dv = attd[col];
            #pragma unroll
            for (int reg = 0; reg < 4; reg++){
                tile[wave][quad*4+reg][col]    = f2fp8(acc0[reg]);
                tile[wave][16+quad*4+reg][col] = f2fp8(acc1[reg]);
                ss0[reg] += acc0[reg] * sv;  dd0[reg] += acc0[reg] * dv;
                ss1[reg] += acc1[reg] * sv;  dd1[reg] += acc1[reg] * dv;
            }
            #pragma unroll
            for (int ks = 0; ks < 4; ks++){ bh[ks] = nh[ks]; bl[ks] = nl[ks]; }
        }
        #pragma unroll
        for (int reg = 0; reg < 4; reg++){
            float a = ss0[reg], b = dd0[reg], c = ss1[reg], d = dd1[reg];
            a += __shfl_xor(a,1,64); a += __shfl_xor(a,2,64); a += __shfl_xor(a,4,64); a += __shfl_xor(a,8,64);
            b += __shfl_xor(b,1,64); b += __shfl_xor(b,2,64); b += __shfl_xor(b,4,64); b += __shfl_xor(b,8,64);
            c += __shfl_xor(c,1,64); c += __shfl_xor(c,2,64); c += __shfl_xor(c,4,64); c += __shfl_xor(c,8,64);
            d += __shfl_xor(d,1,64); d += __shfl_xor(d,2,64); d += __shfl_xor(d,4,64); d += __shfl_xor(d,8,64);
            if (lidx == 0){
                sc[wave][quad*4+reg][h]    = a;  dc[wave][quad*4+reg][h]    = b;
                sc[wave][16+quad*4+reg][h] = c;  dc[wave][16+quad*4+reg][h] = d;
            }
        }
    }
    __syncthreads();
    // coalesced xhb stores: one contiguous 256 B store per row (uint per lane)
    for (int r = 0; r < 32; r++){
        int row = m0 + r;
        if (row < N_NODES){
            unsigned int p = *(const unsigned int*)&tile[wave][r][lane * 4];
            xhb[(size_t)row * 64 + lane] = p;
        }
    }
    {
        int linear = lane * 4;                 // r*8 + h, all 4 in same row
        int row = m0 + (linear >> 3);
        if (row < N_NODES){
            const float* sb = &sc[wave][0][0];
            const float* db = &dc[wave][0][0];
            float4 s4 = *(const float4*)(sb + linear);
            float4 d4 = *(const float4*)(db + linear);
            *(float4*)(a_s + (size_t)m0 * NH + linear) = s4;
            *(float4*)(a_d + (size_t)m0 * NH + linear) = d4;
        }
    }
}

// ---- per-1024-chunk sums (+ rowp[N] sentinel) ----
__global__ void k_bsum(const int* __restrict__ deg, int* __restrict__ bsum, int* __restrict__ rowp){
    int b = blockIdx.x;
    int v = 0;
    for (int i = threadIdx.x; i < 1024; i += 256){
        int idx = b * 1024 + i;
        if (idx < N_NODES) v += deg[idx];
    }
    #pragma unroll
    for (int off = 1; off < 64; off <<= 1) v += __shfl_xor(v, off, 64);
    __shared__ int sd[4];
    if ((threadIdx.x & 63) == 0) sd[threadIdx.x >> 6] = v;
    __syncthreads();
    if (threadIdx.x == 0){
        bsum[b] = sd[0] + sd[1] + sd[2] + sd[3];
        if (b == 0) rowp[N_NODES] = E_TOT;
    }
}

// ---- per-chunk Hillis-Steele scan -> row_ptr, cursor (chunk prefix computed inline) ----
__global__ __launch_bounds__(1024) void k_scan(const int* __restrict__ deg, const int* __restrict__ bsum,
                                               int* __restrict__ rowp, int* __restrict__ cur){
    __shared__ int sd[1024];
    int b = blockIdx.x;
    int bex = 0;
    for (int j = 0; j < b; j++) bex += bsum[j];   // <=48 uniform scalar loads
    int i = b * 1024 + threadIdx.x;
    int v = (i < N_NODES) ? deg[i] : 0;
    sd[threadIdx.x] = v;
    __syncthreads();
    for (int off = 1; off < 1024; off <<= 1){
        int t = (threadIdx.x >= off) ? sd[threadIdx.x - off] : 0;
        __syncthreads();
        sd[threadIdx.x] += t;
        __syncthreads();
    }
    if (i < N_NODES){
        int excl = sd[threadIdx.x] - v + bex;
        rowp[i] = excl;
        cur[i]  = excl;
    }
}

// ---- scatter edges into CSR (src values, ushort; nontemporal stores) ----
__global__ void k_scatter(const int* __restrict__ ei, int* __restrict__ cur,
                          unsigned short* __restrict__ col){
    int e = blockIdx.x * 256 + threadIdx.x;
    if (e >= E_TOT) return;
    int s, d;
    if (e < N_EDGES){ s = ei[e]; d = ei[N_EDGES + e]; }
    else { s = e - N_EDGES; d = s; }
    int slot = atomicAdd(cur + d, 1);
    __builtin_nontemporal_store((unsigned short)s, &col[slot]);
}

// ---- layer-1 aggregation FUSED with layer-2 projection + scores ----
// 2 nodes per wave (32 lanes each, uint2 fp8 gathers), unroll x8 for MLP
__global__ __launch_bounds__(256) void k_agg1f(const unsigned int* __restrict__ xhb,
                                               const float* __restrict__ a_s, const float* __restrict__ a_d,
                                               const int* __restrict__ rowp, const unsigned short* __restrict__ colb,
                                               const float* __restrict__ b1, const float* __restrict__ W2t,
                                               const float* __restrict__ as2, const float* __restrict__ ad2,
                                               float* __restrict__ xh2){
    int wave = threadIdx.x >> 6, lane = threadIdx.x & 63;
    int half = lane >> 5, l32 = lane & 31;
    int n = blockIdx.x * 8 + wave * 2 + half;       // grid covers exactly 50000
    int h = l32 >> 2;
    float adh = a_d[(unsigned)(n * NH + h)];
    int s0 = rowp[n], s1 = rowp[n + 1];
    const uint2* xv = (const uint2*)xhb;            // row = 32 uint2
    f32x2 a01 = {0.f,0.f}, a23 = {0.f,0.f}, a45 = {0.f,0.f}, a67 = {0.f,0.f};
    float den = 0.f;
    int idx = s0;
    for (; idx + 7 < s1; idx += 8){
        int   sE[8]; float eE[8]; uint2 pE[8]; float wE[8];
        #pragma unroll
        for (int j = 0; j < 8; j++) sE[j] = colb[idx + j];
        #pragma unroll
        for (int j = 0; j < 8; j++) eE[j] = a_s[(unsigned)(sE[j] * NH + h)];
        #pragma unroll
        for (int j = 0; j < 8; j++) pE[j] = xv[(unsigned)(sE[j] * 32 + l32)];
        #pragma unroll
        for (int j = 0; j < 8; j++){ wE[j] = __expf(lrelu(eE[j] + adh)); den += wE[j]; }
        #pragma unroll
        for (int j = 0; j < 8; j++){
            f32x2 w2; w2[0] = wE[j]; w2[1] = wE[j];
            a01 += w2 * __builtin_amdgcn_cvt_pk_f32_fp8(pE[j].x, false);
            a23 += w2 * __builtin_amdgcn_cvt_pk_f32_fp8(pE[j].x, true);
            a45 += w2 * __builtin_amdgcn_cvt_pk_f32_fp8(pE[j].y, false);
            a67 += w2 * __builtin_amdgcn_cvt_pk_f32_fp8(pE[j].y, true);
        }
    }
    for (; idx < s1; idx++){
        int sA = colb[idx];
        float wA = __expf(lrelu(a_s[(unsigned)(sA * NH + h)] + adh));
        den += wA;
        uint2 pA = xv[(unsigned)(sA * 32 + l32)];
        f32x2 w2; w2[0] = wA; w2[1] = wA;
        a01 += w2 * __builtin_amdgcn_cvt_pk_f32_fp8(pA.x, false);
        a23 += w2 * __builtin_amdgcn_cvt_pk_f32_fp8(pA.x, true);
        a45 += w2 * __builtin_amdgcn_cvt_pk_f32_fp8(pA.y, false);
        a67 += w2 * __builtin_amdgcn_cvt_pk_f32_fp8(pA.y, true);
    }
    float rden = 1.f / den;
    const float4* b4 = (const float4*)b1;
    float4 bb0 = b4[l32 * 2], bb1 = b4[l32 * 2 + 1];
    float r0 = elu1(a01[0] * rden + bb0.x);
    float r1 = elu1(a01[1] * rden + bb0.y);
    float r2 = elu1(a23[0] * rden + bb0.z);
    float r3 = elu1(a23[1] * rden + bb0.w);
    float r4 = elu1(a45[0] * rden + bb1.x);
    float r5 = elu1(a45[1] * rden + bb1.y);
    float r6 = elu1(a67[0] * rden + bb1.z);
    float r7 = elu1(a67[1] * rden + bb1.w);
    // fused layer-2 projection: o[c] = h1[n] . W2[:,c]  (reduce within 32-lane half)
    float o[C_OUT];
    #pragma unroll
    for (int c = 0; c < C_OUT; c++){
        const float4* w4 = (const float4*)(W2t + c * HC);
        float4 w0 = w4[l32 * 2], w1 = w4[l32 * 2 + 1];
        float v = r0*w0.x + r1*w0.y + r2*w0.z + r3*w0.w
                + r4*w1.x + r5*w1.y + r6*w1.z + r7*w1.w;
        v += __shfl_xor(v, 1, 64); v += __shfl_xor(v, 2, 64); v += __shfl_xor(v, 4, 64);
        v += __shfl_xor(v, 8, 64); v += __shfl_xor(v, 16, 64);
        o[c] = v;
    }
    if (l32 == 0){
        float s2 = 0.f, d2 = 0.f;
        #pragma unroll
        for (int c = 0; c < C_OUT; c++){ s2 += o[c] * as2[c]; d2 += o[c] * ad2[c]; }
        float* xr = xh2 + (unsigned)(n * XSTRIDE);
        *(float4*)(xr)     = make_float4(o[0], o[1], o[2], o[3]);
        *(float4*)(xr + 4) = make_float4(o[4], o[5], o[6], o[7]);
        *(float4*)(xr + 8) = make_float4(o[8], o[9], s2, d2);
    }
}

// ---- layer-2 aggregation + elu -> h2[N,10]; 16 lanes per node, 64B-line rows ----
__global__ __launch_bounds__(256) void k_agg2(const float* __restrict__ xh2,
                                              const int* __restrict__ rowp, const unsigned short* __restrict__ colb,
                                              const float* __restrict__ b2,
                                              float* __restrict__ h2){
    int grp = threadIdx.x >> 4, l16 = threadIdx.x & 15;
    int n = blockIdx.x * 16 + grp;
    if (n >= N_NODES) return;
    float adn = xh2[(unsigned)(n * XSTRIDE + 11)];
    int s0 = rowp[n], s1 = rowp[n + 1];
    float acc[C_OUT] = {};
    float den = 0.f;
    for (int idx = s0 + l16; idx < s1; idx += 16){
        int s = colb[idx];
        const float* xr = xh2 + (unsigned)(s * XSTRIDE);
        float4 q0 = *(const float4*)(xr);
        float4 q1 = *(const float4*)(xr + 4);
        float4 q2 = *(const float4*)(xr + 8);
        float w = __expf(lrelu(q2.z + adn));
        den += w;
        acc[0] += w*q0.x; acc[1] += w*q0.y; acc[2] += w*q0.z; acc[3] += w*q0.w;
        acc[4] += w*q1.x; acc[5] += w*q1.y; acc[6] += w*q1.z; acc[7] += w*q1.w;
        acc[8] += w*q2.x; acc[9] += w*q2.y;
    }
    #pragma unroll
    for (int off = 1; off < 16; off <<= 1){
        den += __shfl_xor(den, off, 64);
        #pragma unroll
        for (int c = 0; c < C_OUT; c++) acc[c] += __shfl_xor(acc[c], off, 64);
    }
    if (l16 == 0){
        float rden = 1.f / den;
        #pragma unroll
        for (int c = 0; c < C_OUT; c++)
            h2[(unsigned)(n * C_OUT + c)] = elu1(acc[c] * rden + b2[c]);
    }
}

// ---- pooling + log_softmax: one block per graph (batch is sorted) ----
__global__ __launch_bounds__(256) void k_pool(const float* __restrict__ h2, const int* __restrict__ batch,
                                              float* __restrict__ out){
    int g = blockIdx.x;
    int l = 0, r = N_NODES;
    while (l < r){ int m = (l + r) >> 1; if (batch[m] < g) l = m + 1; else r = m; }
    int lo = l;
    l = 0; r = N_NODES;
    while (l < r){ int m = (l + r) >> 1; if (batch[m] < g + 1) l = m + 1; else r = m; }
    int hi = l;
    float acc[C_OUT] = {};
    for (int i = lo + (int)threadIdx.x; i < hi; i += 256){
        const float* row = h2 + (size_t)i * C_OUT;
        #pragma unroll
        for (int c = 0; c < C_OUT; c++) acc[c] += row[c];
    }
    #pragma unroll
    for (int c = 0; c < C_OUT; c++){
        #pragma unroll
        for (int off = 32; off > 0; off >>= 1) acc[c] += __shfl_xor(acc[c], off, 64);
    }
    __shared__ float sd[4][C_OUT];
    int wave = threadIdx.x >> 6, lane = threadIdx.x & 63;
    if (lane == 0){
        #pragma unroll
        for (int c = 0; c < C_OUT; c++) sd[wave][c] = acc[c];
    }
    __syncthreads();
    if (threadIdx.x == 0){
        float cnt = (float)(hi - lo);
        if (cnt < 1.f) cnt = 1.f;
        float v[C_OUT];
        float m = -1e30f;
        #pragma unroll
        for (int c = 0; c < C_OUT; c++){
            v[c] = (sd[0][c] + sd[1][c] + sd[2][c] + sd[3][c]) / cnt;
            m = fmaxf(m, v[c]);
        }
        float sum = 0.f;
        #pragma unroll
        for (int c = 0; c < C_OUT; c++) sum += __expf(v[c] - m);
        float lse = m + __logf(sum);
        #pragma unroll
        for (int c = 0; c < C_OUT; c++) out[g * C_OUT + c] = v[c] - lse;
    }
}

extern "C" void kernel_launch(void* const* d_in, const int* in_sizes, int n_in,
                              void* d_out, int out_size, void* d_ws, size_t ws_size,
                              hipStream_t stream){
    const float* x    = (const float*)d_in[0];
    const int*   ei   = (const int*)d_in[1];
    const int*   batch= (const int*)d_in[2];
    const float* W1   = (const float*)d_in[3];
    const float* as1  = (const float*)d_in[4];
    const float* ad1  = (const float*)d_in[5];
    const float* b1   = (const float*)d_in[6];
    const float* W2   = (const float*)d_in[7];
    const float* as2v = (const float*)d_in[8];
    const float* ad2v = (const float*)d_in[9];
    const float* b2   = (const float*)d_in[10];
    float* out = (float*)d_out;

    char* ws = (char*)d_ws;
    size_t off = 0;
    auto alloc = [&](size_t bytes)->char*{
        char* p = ws + off;
        off = (off + bytes + 255) & ~(size_t)255;
        return p;
    };
    unsigned int* xhb  = (unsigned int*)alloc((size_t)N_NODES * HC);           // fp8, 12.8 MB
    unsigned short* bt = (unsigned short*)alloc((size_t)HC * 256 * 2);         // 131 KB [hi|lo]
    float* asc1 = (float*)alloc((size_t)N_NODES * NH * 4);
    float* adc1 = (float*)alloc((size_t)N_NODES * NH * 4);
    int*   deg  = (int*)alloc((size_t)N_NODES * 4);
    int*   rowp = (int*)alloc((size_t)(N_NODES + 1) * 4);
    int*   cur  = (int*)alloc((size_t)N_NODES * 4);
    unsigned short* colb = (unsigned short*)alloc((size_t)E_TOT * 2);          // ushort CSR
    int*   bsum = (int*)alloc(64 * 4);
    float* xh2  = (float*)alloc((size_t)N_NODES * XSTRIDE * 4);                // 3.2 MB
    float* W2t  = (float*)alloc((size_t)HC * C_OUT * 4);
    float* h2   = (float*)alloc((size_t)N_NODES * C_OUT * 4);
    (void)ws_size; (void)in_sizes; (void)n_in; (void)out_size;

    hipMemsetAsync(deg, 0, (size_t)N_NODES * 4, stream);
    hipLaunchKernelGGL(k_setup,   dim3(NB_DEG + 129), dim3(256), 0, stream, ei, deg, W1, bt, W2, W2t);
    hipLaunchKernelGGL(k_gemm1m,  dim3(391),   dim3(256), 0, stream, x, bt, as1, ad1, xhb, asc1, adc1);
    hipLaunchKernelGGL(k_bsum,    dim3(NBLK),  dim3(256), 0, stream, deg, bsum, rowp);
    hipLaunchKernelGGL(k_scan,    dim3(NBLK),  dim3(1024),0, stream, deg, bsum, rowp, cur);
    hipLaunchKernelGGL(k_scatter, dim3((E_TOT + 255)/256), dim3(256), 0, stream, ei, cur, colb);
    hipLaunchKernelGGL(k_agg1f,   dim3(N_NODES / 8), dim3(256), 0, stream, xhb, asc1, adc1, rowp, colb, b1, W2t, as2v, ad2v, xh2);
    hipLaunchKernelGGL(k_agg2,    dim3((N_NODES + 15)/16), dim3(256), 0, stream, xh2, rowp, colb, b2, h2);
    hipLaunchKernelGGL(k_pool,    dim3(N_GRAPH), dim3(256), 0, stream, h2, batch, out);
}

// Round 17
// 280.949 us; speedup vs baseline: 1.0719x; 1.0719x over previous
//
#include <hip/hip_runtime.h>

#define N_NODES 50000
#define N_EDGES 800000
#define E_TOT   850000
#define F_IN    128
#define HC      256      // H * C_hid
#define NH      8
#define C_OUT   10
#define N_GRAPH 128
#define NBLK    49       // ceil(N_NODES / 1024)
#define XSTRIDE 16       // xh2 row stride: [o0..o9, s2, d2, pad x4] = one 64B line
#define NB_DEG  3322     // ceil(E_TOT / 256)

typedef __attribute__((ext_vector_type(8))) short bf16x8;
typedef __attribute__((ext_vector_type(4))) float f32x4;
typedef __attribute__((ext_vector_type(2))) float f32x2;

__device__ __forceinline__ float lrelu(float x){ return x > 0.f ? x : 0.2f * x; }
__device__ __forceinline__ float elu1(float x){ return x > 0.f ? x : (__expf(x) - 1.f); }

__device__ __forceinline__ unsigned short f2bf(float f){
    unsigned int u = __float_as_uint(f);
    return (unsigned short)((u + 0x7fffu + ((u >> 16) & 1u)) >> 16);
}
__device__ __forceinline__ float bf2f(unsigned short h){
    return __uint_as_float((unsigned int)h << 16);
}
// fp8 e4m3 (OCP) encode via HW converter, RNE
__device__ __forceinline__ unsigned char f2fp8(float v){
    unsigned int t = __builtin_amdgcn_cvt_pk_fp8_f32(v, 0.f, 0, false);
    return (unsigned char)(t & 0xffu);
}

// ---- setup: deg histogram (deg pre-zeroed by memsetAsync) + B split build + W2 transpose ----
__global__ void k_setup(const int* __restrict__ ei, int* __restrict__ deg,
                        const float* __restrict__ W1, unsigned short* __restrict__ bt,
                        const float* __restrict__ W2, float* __restrict__ W2t){
    int b = blockIdx.x;
    if (b < NB_DEG){
        int e = b * 256 + threadIdx.x;
        if (e < E_TOT){
            int dst = (e < N_EDGES) ? ei[N_EDGES + e] : (e - N_EDGES);
            atomicAdd(deg + dst, 1);
        }
    } else if (b < NB_DEG + 128){
        int k = b - NB_DEG;           // 0..127
        int c = threadIdx.x;          // 0..255
        float v = W1[k * HC + c];
        unsigned short hi = f2bf(v);
        unsigned short lo = f2bf(v - bf2f(hi));
        bt[(size_t)c * 256 + k]       = hi;   // col-major: [hi(128) | lo(128)] per col
        bt[(size_t)c * 256 + 128 + k] = lo;
    } else {
        for (int j = threadIdx.x; j < HC * C_OUT; j += 256){
            int k = j / C_OUT, c = j % C_OUT;
            W2t[c * HC + k] = W2[j];
        }
    }
}

// ---- GEMM1 via MFMA (R13-best): 32 rows/wave, 3-way accumulator ILP split,
//      software-prefetched B, fp8 C-tile in LDS, contiguous 256 B row stores ----
__global__ __launch_bounds__(256) void k_gemm1m(const float* __restrict__ x,
                                                const unsigned short* __restrict__ bt,
                                                const float* __restrict__ atts,
                                                const float* __restrict__ attd,
                                                unsigned int* __restrict__ xhb,   // fp8 rows, 64 uints
                                                float* __restrict__ a_s,
                                                float* __restrict__ a_d){
    __shared__ unsigned char tile[4][32][264];    // fp8 C-tile per wave (33.8 KB)
    __shared__ float sc[4][32][8], dc[4][32][8];  // per-row per-head scores (8 KB)
    const int wave = threadIdx.x >> 6, lane = threadIdx.x & 63;
    const int quad = lane >> 4, lidx = lane & 15;
    const int m0 = blockIdx.x * 128 + wave * 32;
    int ar0 = m0 + lidx;      if (ar0 >= N_NODES) ar0 = N_NODES - 1;
    int ar1 = m0 + 16 + lidx; if (ar1 >= N_NODES) ar1 = N_NODES - 1;

    // load x rows, split into hi/lo bf16 fragments in-register
    bf16x8 ah0[4], al0[4], ah1[4], al1[4];
    #pragma unroll
    for (int ks = 0; ks < 4; ks++){
        const float* p0 = x + (size_t)ar0 * F_IN + ks * 32 + quad * 8;
        const float* p1 = x + (size_t)ar1 * F_IN + ks * 32 + quad * 8;
        float4 u0 = *(const float4*)p0, u1 = *(const float4*)(p0 + 4);
        float4 w0 = *(const float4*)p1, w1 = *(const float4*)(p1 + 4);
        float v0[8] = {u0.x,u0.y,u0.z,u0.w,u1.x,u1.y,u1.z,u1.w};
        float v1[8] = {w0.x,w0.y,w0.z,w0.w,w1.x,w1.y,w1.z,w1.w};
        bf16x8 h0v, l0v, h1v, l1v;
        #pragma unroll
        for (int j = 0; j < 8; j++){
            unsigned short hh = f2bf(v0[j]);
            h0v[j] = (short)hh;
            l0v[j] = (short)f2bf(v0[j] - bf2f(hh));
            unsigned short hg = f2bf(v1[j]);
            h1v[j] = (short)hg;
            l1v[j] = (short)f2bf(v1[j] - bf2f(hg));
        }
        ah0[ks] = h0v; al0[ks] = l0v; ah1[ks] = h1v; al1[ks] = l1v;
    }

    const uint4* bbase = (const uint4*)bt;        // col stride = 512 B = 32 uint4
    // preload B for t=0 (h=0, sub=0)
    bf16x8 bh[4], bl[4];
    {
        const uint4* bcol = bbase + (size_t)lidx * 32 + quad;
        #pragma unroll
        for (int ks = 0; ks < 4; ks++){
            bh[ks] = __builtin_bit_cast(bf16x8, bcol[ks * 4]);
            bl[ks] = __builtin_bit_cast(bf16x8, bcol[16 + ks * 4]);
        }
    }
    for (int h = 0; h < NH; h++){
        float ss0[4] = {0,0,0,0}, ss1[4] = {0,0,0,0};
        float dd0[4] = {0,0,0,0}, dd1[4] = {0,0,0,0};
        #pragma unroll
        for (int sub = 0; sub < 2; sub++){
            int col = h * 32 + sub * 16 + lidx;
            // prefetch next (h,sub)'s B before issuing this tile's MFMAs
            bf16x8 nh[4], nl[4];
            int tn = h * 2 + sub + 1;
            if (tn < 16){
                int ncol = (tn >> 1) * 32 + (tn & 1) * 16 + lidx;
                const uint4* nb = bbase + (size_t)ncol * 32 + quad;
                #pragma unroll
                for (int ks = 0; ks < 4; ks++){
                    nh[ks] = __builtin_bit_cast(bf16x8, nb[ks * 4]);
                    nl[ks] = __builtin_bit_cast(bf16x8, nb[16 + ks * 4]);
                }
            }
            // 3-way ILP split: chains of depth 4 instead of 12
            f32x4 a0A = {0.f,0.f,0.f,0.f}, a0B = {0.f,0.f,0.f,0.f}, a0C = {0.f,0.f,0.f,0.f};
            f32x4 a1A = {0.f,0.f,0.f,0.f}, a1B = {0.f,0.f,0.f,0.f}, a1C = {0.f,0.f,0.f,0.f};
            #pragma unroll
            for (int ks = 0; ks < 4; ks++){
                a0A = __builtin_amdgcn_mfma_f32_16x16x32_bf16(ah0[ks], bh[ks], a0A, 0, 0, 0);
                a1A = __builtin_amdgcn_mfma_f32_16x16x32_bf16(ah1[ks], bh[ks], a1A, 0, 0, 0);
                a0B = __builtin_amdgcn_mfma_f32_16x16x32_bf16(ah0[ks], bl[ks], a0B, 0, 0, 0);
                a1B = __builtin_amdgcn_mfma_f32_16x16x32_bf16(ah1[ks], bl[ks], a1B, 0, 0, 0);
                a0C = __builtin_amdgcn_mfma_f32_16x16x32_bf16(al0[ks], bh[ks], a0C, 0, 0, 0);
                a1C = __builtin_amdgcn_mfma_f32_16x16x32_bf16(al1[ks], bh[ks], a1C, 0, 0, 0);
            }
            f32x4 acc0, acc1;
            #pragma unroll
            for (int reg = 0; reg < 4; reg++){
                acc0[reg] = (a0A[reg] + a0B[reg]) + a0C[reg];
                acc1[reg] = (a1A[reg] + a1B[reg]) + a1C[reg];
            }
            float sv = atts[col], dv = attd[col];
            #pragma unroll
            for (int reg = 0; reg < 4; reg++){
                tile[wave][quad*4+reg][col]    = f2fp8(acc0[reg]);
                tile[wave][16+quad*4+reg][col] = f2fp8(acc1[reg]);
                ss0[reg] += acc0[reg] * sv;  dd0[reg] += acc0[reg] * dv;
                ss1[reg] += acc1[reg] * sv;  dd1[reg] += acc1[reg] * dv;
            }
            #pragma unroll
            for (int ks = 0; ks < 4; ks++){ bh[ks] = nh[ks]; bl[ks] = nl[ks]; }
        }
        #pragma unroll
        for (int reg = 0; reg < 4; reg++){
            float a = ss0[reg], b = dd0[reg], c = ss1[reg], d = dd1[reg];
            a += __shfl_xor(a,1,64); a += __shfl_xor(a,2,64); a += __shfl_xor(a,4,64); a += __shfl_xor(a,8,64);
            b += __shfl_xor(b,1,64); b += __shfl_xor(b,2,64); b += __shfl_xor(b,4,64); b += __shfl_xor(b,8,64);
            c += __shfl_xor(c,1,64); c += __shfl_xor(c,2,64); c += __shfl_xor(c,4,64); c += __shfl_xor(c,8,64);
            d += __shfl_xor(d,1,64); d += __shfl_xor(d,2,64); d += __shfl_xor(d,4,64); d += __shfl_xor(d,8,64);
            if (lidx == 0){
                sc[wave][quad*4+reg][h]    = a;  dc[wave][quad*4+reg][h]    = b;
                sc[wave][16+quad*4+reg][h] = c;  dc[wave][16+quad*4+reg][h] = d;
            }
        }
    }
    __syncthreads();
    // coalesced xhb stores: one contiguous 256 B store per row (uint per lane)
    for (int r = 0; r < 32; r++){
        int row = m0 + r;
        if (row < N_NODES){
            unsigned int p = *(const unsigned int*)&tile[wave][r][lane * 4];
            xhb[(size_t)row * 64 + lane] = p;
        }
    }
    {
        int linear = lane * 4;                 // r*8 + h, all 4 in same row
        int row = m0 + (linear >> 3);
        if (row < N_NODES){
            const float* sb = &sc[wave][0][0];
            const float* db = &dc[wave][0][0];
            float4 s4 = *(const float4*)(sb + linear);
            float4 d4 = *(const float4*)(db + linear);
            *(float4*)(a_s + (size_t)m0 * NH + linear) = s4;
            *(float4*)(a_d + (size_t)m0 * NH + linear) = d4;
        }
    }
}

// ---- per-1024-chunk sums (+ rowp[N] sentinel) ----
__global__ void k_bsum(const int* __restrict__ deg, int* __restrict__ bsum, int* __restrict__ rowp){
    int b = blockIdx.x;
    int v = 0;
    for (int i = threadIdx.x; i < 1024; i += 256){
        int idx = b * 1024 + i;
        if (idx < N_NODES) v += deg[idx];
    }
    #pragma unroll
    for (int off = 1; off < 64; off <<= 1) v += __shfl_xor(v, off, 64);
    __shared__ int sd[4];
    if ((threadIdx.x & 63) == 0) sd[threadIdx.x >> 6] = v;
    __syncthreads();
    if (threadIdx.x == 0){
        bsum[b] = sd[0] + sd[1] + sd[2] + sd[3];
        if (b == 0) rowp[N_NODES] = E_TOT;
    }
}

// ---- per-chunk Hillis-Steele scan -> row_ptr, cursor (chunk prefix computed inline) ----
__global__ __launch_bounds__(1024) void k_scan(const int* __restrict__ deg, const int* __restrict__ bsum,
                                               int* __restrict__ rowp, int* __restrict__ cur){
    __shared__ int sd[1024];
    int b = blockIdx.x;
    int bex = 0;
    for (int j = 0; j < b; j++) bex += bsum[j];   // <=48 uniform scalar loads
    int i = b * 1024 + threadIdx.x;
    int v = (i < N_NODES) ? deg[i] : 0;
    sd[threadIdx.x] = v;
    __syncthreads();
    for (int off = 1; off < 1024; off <<= 1){
        int t = (threadIdx.x >= off) ? sd[threadIdx.x - off] : 0;
        __syncthreads();
        sd[threadIdx.x] += t;
        __syncthreads();
    }
    if (i < N_NODES){
        int excl = sd[threadIdx.x] - v + bex;
        rowp[i] = excl;
        cur[i]  = excl;
    }
}

// ---- scatter edges into CSR (src values, ushort; plain stores — NT regressed) ----
__global__ void k_scatter(const int* __restrict__ ei, int* __restrict__ cur,
                          unsigned short* __restrict__ col){
    int e = blockIdx.x * 256 + threadIdx.x;
    if (e >= E_TOT) return;
    int s, d;
    if (e < N_EDGES){ s = ei[e]; d = ei[N_EDGES + e]; }
    else { s = e - N_EDGES; d = s; }
    int slot = atomicAdd(cur + d, 1);
    col[slot] = (unsigned short)s;
}

// ---- layer-1 aggregation FUSED with layer-2 projection + scores ----
// 2 nodes per wave (32 lanes each, uint2 fp8 gathers), unroll x4 (R15-best), packed FMAs
__global__ __launch_bounds__(256) void k_agg1f(const unsigned int* __restrict__ xhb,
                                               const float* __restrict__ a_s, const float* __restrict__ a_d,
                                               const int* __restrict__ rowp, const unsigned short* __restrict__ colb,
                                               const float* __restrict__ b1, const float* __restrict__ W2t,
                                               const float* __restrict__ as2, const float* __restrict__ ad2,
                                               float* __restrict__ xh2){
    int wave = threadIdx.x >> 6, lane = threadIdx.x & 63;
    int half = lane >> 5, l32 = lane & 31;
    int n = blockIdx.x * 8 + wave * 2 + half;       // grid covers exactly 50000
    int h = l32 >> 2;
    float adh = a_d[(unsigned)(n * NH + h)];
    int s0 = rowp[n], s1 = rowp[n + 1];
    const uint2* xv = (const uint2*)xhb;            // row = 32 uint2
    f32x2 a01 = {0.f,0.f}, a23 = {0.f,0.f}, a45 = {0.f,0.f}, a67 = {0.f,0.f};
    float den = 0.f;
    int idx = s0;
    for (; idx + 3 < s1; idx += 4){
        int sA = colb[idx], sB = colb[idx+1], sC = colb[idx+2], sD = colb[idx+3];
        float eA = a_s[(unsigned)(sA * NH + h)];
        float eB = a_s[(unsigned)(sB * NH + h)];
        float eC = a_s[(unsigned)(sC * NH + h)];
        float eD = a_s[(unsigned)(sD * NH + h)];
        uint2 pA = xv[(unsigned)(sA * 32 + l32)];
        uint2 pB = xv[(unsigned)(sB * 32 + l32)];
        uint2 pC = xv[(unsigned)(sC * 32 + l32)];
        uint2 pD = xv[(unsigned)(sD * 32 + l32)];
        float wA = __expf(lrelu(eA + adh));
        float wB = __expf(lrelu(eB + adh));
        float wC = __expf(lrelu(eC + adh));
        float wD = __expf(lrelu(eD + adh));
        den += (wA + wB) + (wC + wD);
        f32x2 w2;
        w2[0] = wA; w2[1] = wA;
        a01 += w2 * __builtin_amdgcn_cvt_pk_f32_fp8(pA.x, false);
        a23 += w2 * __builtin_amdgcn_cvt_pk_f32_fp8(pA.x, true);
        a45 += w2 * __builtin_amdgcn_cvt_pk_f32_fp8(pA.y, false);
        a67 += w2 * __builtin_amdgcn_cvt_pk_f32_fp8(pA.y, true);
        w2[0] = wB; w2[1] = wB;
        a01 += w2 * __builtin_amdgcn_cvt_pk_f32_fp8(pB.x, false);
        a23 += w2 * __builtin_amdgcn_cvt_pk_f32_fp8(pB.x, true);
        a45 += w2 * __builtin_amdgcn_cvt_pk_f32_fp8(pB.y, false);
        a67 += w2 * __builtin_amdgcn_cvt_pk_f32_fp8(pB.y, true);
        w2[0] = wC; w2[1] = wC;
        a01 += w2 * __builtin_amdgcn_cvt_pk_f32_fp8(pC.x, false);
        a23 += w2 * __builtin_amdgcn_cvt_pk_f32_fp8(pC.x, true);
        a45 += w2 * __builtin_amdgcn_cvt_pk_f32_fp8(pC.y, false);
        a67 += w2 * __builtin_amdgcn_cvt_pk_f32_fp8(pC.y, true);
        w2[0] = wD; w2[1] = wD;
        a01 += w2 * __builtin_amdgcn_cvt_pk_f32_fp8(pD.x, false);
        a23 += w2 * __builtin_amdgcn_cvt_pk_f32_fp8(pD.x, true);
        a45 += w2 * __builtin_amdgcn_cvt_pk_f32_fp8(pD.y, false);
        a67 += w2 * __builtin_amdgcn_cvt_pk_f32_fp8(pD.y, true);
    }
    for (; idx < s1; idx++){
        int sA = colb[idx];
        float wA = __expf(lrelu(a_s[(unsigned)(sA * NH + h)] + adh));
        den += wA;
        uint2 pA = xv[(unsigned)(sA * 32 + l32)];
        f32x2 w2; w2[0] = wA; w2[1] = wA;
        a01 += w2 * __builtin_amdgcn_cvt_pk_f32_fp8(pA.x, false);
        a23 += w2 * __builtin_amdgcn_cvt_pk_f32_fp8(pA.x, true);
        a45 += w2 * __builtin_amdgcn_cvt_pk_f32_fp8(pA.y, false);
        a67 += w2 * __builtin_amdgcn_cvt_pk_f32_fp8(pA.y, true);
    }
    float rden = 1.f / den;
    const float4* b4 = (const float4*)b1;
    float4 bb0 = b4[l32 * 2], bb1 = b4[l32 * 2 + 1];
    float r0 = elu1(a01[0] * rden + bb0.x);
    float r1 = elu1(a01[1] * rden + bb0.y);
    float r2 = elu1(a23[0] * rden + bb0.z);
    float r3 = elu1(a23[1] * rden + bb0.w);
    float r4 = elu1(a45[0] * rden + bb1.x);
    float r5 = elu1(a45[1] * rden + bb1.y);
    float r6 = elu1(a67[0] * rden + bb1.z);
    float r7 = elu1(a67[1] * rden + bb1.w);
    // fused layer-2 projection: o[c] = h1[n] . W2[:,c]  (reduce within 32-lane half)
    float o[C_OUT];
    #pragma unroll
    for (int c = 0; c < C_OUT; c++){
        const float4* w4 = (const float4*)(W2t + c * HC);
        float4 w0 = w4[l32 * 2], w1 = w4[l32 * 2 + 1];
        float v = r0*w0.x + r1*w0.y + r2*w0.z + r3*w0.w
                + r4*w1.x + r5*w1.y + r6*w1.z + r7*w1.w;
        v += __shfl_xor(v, 1, 64); v += __shfl_xor(v, 2, 64); v += __shfl_xor(v, 4, 64);
        v += __shfl_xor(v, 8, 64); v += __shfl_xor(v, 16, 64);
        o[c] = v;
    }
    if (l32 == 0){
        float s2 = 0.f, d2 = 0.f;
        #pragma unroll
        for (int c = 0; c < C_OUT; c++){ s2 += o[c] * as2[c]; d2 += o[c] * ad2[c]; }
        float* xr = xh2 + (unsigned)(n * XSTRIDE);
        *(float4*)(xr)     = make_float4(o[0], o[1], o[2], o[3]);
        *(float4*)(xr + 4) = make_float4(o[4], o[5], o[6], o[7]);
        *(float4*)(xr + 8) = make_float4(o[8], o[9], s2, d2);
    }
}

// ---- layer-2 aggregation + elu -> h2[N,10]; 8 lanes per node (3-step reduction) ----
__global__ __launch_bounds__(256) void k_agg2(const float* __restrict__ xh2,
                                              const int* __restrict__ rowp, const unsigned short* __restrict__ colb,
                                              const float* __restrict__ b2,
                                              float* __restrict__ h2){
    int grp = threadIdx.x >> 3, l8 = threadIdx.x & 7;
    int n = blockIdx.x * 32 + grp;
    if (n >= N_NODES) return;
    float adn = xh2[(unsigned)(n * XSTRIDE + 11)];
    int s0 = rowp[n], s1 = rowp[n + 1];
    float acc[C_OUT] = {};
    float den = 0.f;
    for (int idx = s0 + l8; idx < s1; idx += 8){
        int s = colb[idx];
        const float* xr = xh2 + (unsigned)(s * XSTRIDE);
        float4 q0 = *(const float4*)(xr);
        float4 q1 = *(const float4*)(xr + 4);
        float4 q2 = *(const float4*)(xr + 8);
        float w = __expf(lrelu(q2.z + adn));
        den += w;
        acc[0] += w*q0.x; acc[1] += w*q0.y; acc[2] += w*q0.z; acc[3] += w*q0.w;
        acc[4] += w*q1.x; acc[5] += w*q1.y; acc[6] += w*q1.z; acc[7] += w*q1.w;
        acc[8] += w*q2.x; acc[9] += w*q2.y;
    }
    #pragma unroll
    for (int off = 1; off < 8; off <<= 1){
        den += __shfl_xor(den, off, 64);
        #pragma unroll
        for (int c = 0; c < C_OUT; c++) acc[c] += __shfl_xor(acc[c], off, 64);
    }
    if (l8 == 0){
        float rden = 1.f / den;
        #pragma unroll
        for (int c = 0; c < C_OUT; c++)
            h2[(unsigned)(n * C_OUT + c)] = elu1(acc[c] * rden + b2[c]);
    }
}

// ---- pooling + log_softmax: one block per graph (batch is sorted) ----
__global__ __launch_bounds__(256) void k_pool(const float* __restrict__ h2, const int* __restrict__ batch,
                                              float* __restrict__ out){
    int g = blockIdx.x;
    int l = 0, r = N_NODES;
    while (l < r){ int m = (l + r) >> 1; if (batch[m] < g) l = m + 1; else r = m; }
    int lo = l;
    l = 0; r = N_NODES;
    while (l < r){ int m = (l + r) >> 1; if (batch[m] < g + 1) l = m + 1; else r = m; }
    int hi = l;
    float acc[C_OUT] = {};
    for (int i = lo + (int)threadIdx.x; i < hi; i += 256){
        const float* row = h2 + (size_t)i * C_OUT;
        #pragma unroll
        for (int c = 0; c < C_OUT; c++) acc[c] += row[c];
    }
    #pragma unroll
    for (int c = 0; c < C_OUT; c++){
        #pragma unroll
        for (int off = 32; off > 0; off >>= 1) acc[c] += __shfl_xor(acc[c], off, 64);
    }
    __shared__ float sd[4][C_OUT];
    int wave = threadIdx.x >> 6, lane = threadIdx.x & 63;
    if (lane == 0){
        #pragma unroll
        for (int c = 0; c < C_OUT; c++) sd[wave][c] = acc[c];
    }
    __syncthreads();
    if (threadIdx.x == 0){
        float cnt = (float)(hi - lo);
        if (cnt < 1.f) cnt = 1.f;
        float v[C_OUT];
        float m = -1e30f;
        #pragma unroll
        for (int c = 0; c < C_OUT; c++){
            v[c] = (sd[0][c] + sd[1][c] + sd[2][c] + sd[3][c]) / cnt;
            m = fmaxf(m, v[c]);
        }
        float sum = 0.f;
        #pragma unroll
        for (int c = 0; c < C_OUT; c++) sum += __expf(v[c] - m);
        float lse = m + __logf(sum);
        #pragma unroll
        for (int c = 0; c < C_OUT; c++) out[g * C_OUT + c] = v[c] - lse;
    }
}

extern "C" void kernel_launch(void* const* d_in, const int* in_sizes, int n_in,
                              void* d_out, int out_size, void* d_ws, size_t ws_size,
                              hipStream_t stream){
    const float* x    = (const float*)d_in[0];
    const int*   ei   = (const int*)d_in[1];
    const int*   batch= (const int*)d_in[2];
    const float* W1   = (const float*)d_in[3];
    const float* as1  = (const float*)d_in[4];
    const float* ad1  = (const float*)d_in[5];
    const float* b1   = (const float*)d_in[6];
    const float* W2   = (const float*)d_in[7];
    const float* as2v = (const float*)d_in[8];
    const float* ad2v = (const float*)d_in[9];
    const float* b2   = (const float*)d_in[10];
    float* out = (float*)d_out;

    char* ws = (char*)d_ws;
    size_t off = 0;
    auto alloc = [&](size_t bytes)->char*{
        char* p = ws + off;
        off = (off + bytes + 255) & ~(size_t)255;
        return p;
    };
    unsigned int* xhb  = (unsigned int*)alloc((size_t)N_NODES * HC);           // fp8, 12.8 MB
    unsigned short* bt = (unsigned short*)alloc((size_t)HC * 256 * 2);         // 131 KB [hi|lo]
    float* asc1 = (float*)alloc((size_t)N_NODES * NH * 4);
    float* adc1 = (float*)alloc((size_t)N_NODES * NH * 4);
    int*   deg  = (int*)alloc((size_t)N_NODES * 4);
    int*   rowp = (int*)alloc((size_t)(N_NODES + 1) * 4);
    int*   cur  = (int*)alloc((size_t)N_NODES * 4);
    unsigned short* colb = (unsigned short*)alloc((size_t)E_TOT * 2);          // ushort CSR
    int*   bsum = (int*)alloc(64 * 4);
    float* xh2  = (float*)alloc((size_t)N_NODES * XSTRIDE * 4);                // 3.2 MB
    float* W2t  = (float*)alloc((size_t)HC * C_OUT * 4);
    float* h2   = (float*)alloc((size_t)N_NODES * C_OUT * 4);
    (void)ws_size; (void)in_sizes; (void)n_in; (void)out_size;

    hipMemsetAsync(deg, 0, (size_t)N_NODES * 4, stream);
    hipLaunchKernelGGL(k_setup,   dim3(NB_DEG + 129), dim3(256), 0, stream, ei, deg, W1, bt, W2, W2t);
    hipLaunchKernelGGL(k_gemm1m,  dim3(391),   dim3(256), 0, stream, x, bt, as1, ad1, xhb, asc1, adc1);
    hipLaunchKernelGGL(k_bsum,    dim3(NBLK),  dim3(256), 0, stream, deg, bsum, rowp);
    hipLaunchKernelGGL(k_scan,    dim3(NBLK),  dim3(1024),0, stream, deg, bsum, rowp, cur);
    hipLaunchKernelGGL(k_scatter, dim3((E_TOT + 255)/256), dim3(256), 0, stream, ei, cur, colb);
    hipLaunchKernelGGL(k_agg1f,   dim3(N_NODES / 8), dim3(256), 0, stream, xhb, asc1, adc1, rowp, colb, b1, W2t, as2v, ad2v, xh2);
    hipLaunchKernelGGL(k_agg2,    dim3((N_NODES + 31)/32), dim3(256), 0, stream, xh2, rowp, colb, b2, h2);
    hipLaunchKernelGGL(k_pool,    dim3(N_GRAPH), dim3(256), 0, stream, h2, batch, out);
}